// Round 1
// baseline (682.798 us; speedup 1.0000x reference)
//
#include <hip/hip_runtime.h>
#include <stdint.h>
#include <math.h>

#define NB 4096
#define NT 1024

// Output layout (float32, concatenated in return order):
//   yseq_full: [NB][NT][4]  at offset 0
//   yseq:      [NB][NT][2]  at offset NB*NT*4
//   xseq:      [NB][NT][3]  at offset NB*NT*6

#if __has_builtin(__builtin_amdgcn_exp2f)
#define EXP2F __builtin_amdgcn_exp2f
#else
#define EXP2F exp2f
#endif
#if __has_builtin(__builtin_amdgcn_rcpf)
#define RCPF __builtin_amdgcn_rcpf
#else
#define RCPF(x) (1.0f / (x))
#endif

// 2*log2(e): tanh(y) = 1 - 2/(1+exp2(y*TANH_SCALE)). The scale is folded
// into the MLP weights so the tanh chain is exp2 -> add -> rcp -> fma.
#define TANH_SCALE 2.885390081777927f

// DPP move, masked-out lanes read 0 (bound_ctrl=1). Full-rate VALU cross-lane.
template <int CTRL>
__device__ __forceinline__ float dppmov(float x) {
  return __int_as_float(
      __builtin_amdgcn_update_dpp(0, __float_as_int(x), CTRL, 0xF, 0xF, true));
}
// DPP move where non-updated rows KEEP their own value (old = src).
template <int CTRL, int RMASK>
__device__ __forceinline__ float dppmov_keep(float x) {
  return __int_as_float(__builtin_amdgcn_update_dpp(
      __float_as_int(x), __float_as_int(x), CTRL, RMASK, 0xF, false));
}

// rotate-allreduce within each 16-lane row: after ror 8,4,2,1 every lane of
// the row holds the row sum.
__device__ __forceinline__ float rowred1(float a) {
  a += dppmov<0x128>(a);  // row_ror:8
  a += dppmov<0x124>(a);  // row_ror:4
  a += dppmov<0x122>(a);  // row_ror:2
  a += dppmov<0x121>(a);  // row_ror:1
  return a;
}

// row_bcast15 with row_mask=0b1010: lanes 16-31 receive lane 15's value
// (chain A row0 sum) and lanes 48-63 receive lane 47's value (chain B row0
// sum). Rows 0 and 2 are masked off and keep their own value (old = src).
// This is the only cross-row transfer the dynamics need (n1 -> r2 row).
__device__ __forceinline__ float bcast_r1sum(float x) {
  return dppmov_keep<0x142, 0xA>(x);
}

// ---------------------------------------------------------------------------
// Phase 1: sequential x-recurrence.
// NEW LAYOUT: 32 lanes per chain (2 chains per wave).
//   row0 (lanes 0-15):  the 16 hidden units of r1; carries state x0 in xA.
//   row1 (lanes 16-31): the 16 hidden units of r2; carries x1 in xA, x2 in xB.
// One tanh per lane per RK stage (was two), one rowred1 (was rowred2), and a
// single DPP row_bcast15 moves n1 into row1. 4096 chains * 32 lanes =
// 2048 waves = 2 waves/SIMD, so the dependent-chain stalls (36% of cycles at
// 1 wave/SIMD) are filled by the co-resident wave.
// ---------------------------------------------------------------------------
__global__ __launch_bounds__(256) void phase1_kernel(
    const float* __restrict__ u, const float* __restrict__ xz0,
    const float* __restrict__ r1W1, const float* __restrict__ r1b1,
    const float* __restrict__ r1W2, const float* __restrict__ r1b2,
    const float* __restrict__ r2W1, const float* __restrict__ r2b1,
    const float* __restrict__ r2W2, const float* __restrict__ r2b2,
    const float* __restrict__ eCW1, const float* __restrict__ eCb1,
    const float* __restrict__ eCW2, const float* __restrict__ eCb2,
    float* __restrict__ out) {
  const int tid = threadIdx.x;
  const int sub = tid & 31;  // lane within chain
  const int rl = tid & 15;   // hidden-unit index within row
  const bool row1 = (sub & 16) != 0;
  const int chain = (blockIdx.x << 3) + (tid >> 5);  // 8 chains per block

  // per-lane MLP weights (tanh scale folded in)
  float wA, wB, wC, wP;
  if (!row1) {
    wA = r1W1[rl] * TANH_SCALE;
    wB = 0.0f;  // row0 has no second input
    wC = r1b1[rl] * TANH_SCALE;
    wP = r1W2[rl];
  } else {
    wA = r2W1[rl] * TANH_SCALE;       // weight on s1 (= xA of row1)
    wB = r2W1[16 + rl] * TANH_SCALE;  // weight on s2 (= xB of row1)
    wC = r2b1[rl] * TANH_SCALE;
    wP = r2W2[rl];
  }
  const float wPn2 = -2.0f * wP;
  const float c1 = r1b2[0];
  const float c2 = r2b2[0];

  // Per-lane k coefficients (normalization constants folded, same algebra as
  // the verified 16-lane kernel):
  //   row0: kA = k0 = a_u      - 0.1*s0 - 1*n1 + 0*n2 ;  kB = 0 (dummy)
  //   row1: kA = k1 = -0.2     - 0.1*s1 + 1.5*n1 - 3*n2
  //         kB = k2 = -0.2     - 0.1*s2 + 0*n1  + 1*n2
  const float gA1 = row1 ? 1.5f : -1.0f;
  const float gA2 = row1 ? -3.0f : 0.0f;
  const float mB = row1 ? -0.1f : 0.0f;
  const float cBc = row1 ? -0.2f : 0.0f;
  const float gB2 = row1 ? 1.0f : 0.0f;
  // cA per step: row0 gets a_u = u/6 + 1/6, row1 gets -0.2 (one fma, no sel)
  const float uCoef = row1 ? 0.0f : (1.0f / 6.0f);
  const float uBias = row1 ? -0.2f : (1.0f / 6.0f);

  const float* xzr = xz0 + chain * 18;
  float xA = row1 ? xzr[1] : xzr[0];

  // Cc0 = eC(z0): 32 hidden units, one per chain lane. Row sums combined via
  // ds_swizzle xor-16 (one-time, init only).
  float h0 = eCb1[sub];
#pragma unroll
  for (int i = 0; i < 15; ++i)
    h0 = __builtin_fmaf(xzr[3 + i], eCW1[i * 32 + sub], h0);
  const float e0 = EXP2F(h0 * TANH_SCALE);
  const float r0 = RCPF(e0 + 1.0f);
  float p0 = __builtin_fmaf(-2.0f * eCW2[sub], r0, eCW2[sub]);
  p0 = rowred1(p0);
  const float q0 = __int_as_float(
      __builtin_amdgcn_ds_swizzle(__float_as_int(p0), 0x401F));  // lane ^= 16
  const float x2init = p0 + q0 + eCb2[0];
  float xB = row1 ? x2init : 0.0f;  // row0 xB stays exactly 0 (finite dummy)

  const float* urow = u + (size_t)chain * NT;
  const int ro = row1 ? 1 : 0;  // row1 leader stores the +1 column
  float* yfb = out + (size_t)chain * NT * 4 + ro;
  float* ysb = out + (size_t)NB * NT * 4 + (size_t)chain * NT * 2 + ro;
  float* xsb = out + (size_t)NB * NT * 6 + (size_t)chain * NT * 3 + ro;

  // one RK stage: per-lane h -> tanh (folded) -> row allreduce -> bcast n1
  auto fxu = [&](float sA, float sB, float cA, float& kA, float& kB) {
    float h = __builtin_fmaf(sB, wB, wC);
    h = __builtin_fmaf(sA, wA, h);
    const float e = EXP2F(h);
    const float r = RCPF(e + 1.0f);
    float p = __builtin_fmaf(wPn2, r, wP);  // wP*tanh(h), fold the mul
    p = rowred1(p);                         // row0: P1, row1: P2 (all lanes)
    const float n1 = bcast_r1sum(p) + c1;   // P1 everywhere
    const float n2 = p + c2;                // valid on row1; row0: unused
    kA = __builtin_fmaf(-0.1f, sA, cA);
    kA = __builtin_fmaf(gA1, n1, kA);
    kA = __builtin_fmaf(gA2, n2, kA);
    kB = __builtin_fmaf(mB, sB, cBc);
    kB = __builtin_fmaf(gB2, n2, kB);
  };

  float4 ucur = *(const float4*)urow;
  for (int t4 = 0; t4 < NT; t4 += 4) {
    const int tn = (t4 + 4 < NT) ? (t4 + 4) : (NT - 4);
    const float4 unext = *(const float4*)(urow + tn);  // prefetch next group
    const float us[4] = {ucur.x, ucur.y, ucur.z, ucur.w};
#pragma unroll
    for (int e = 0; e < 4; ++e) {
      const int t = t4 + e;
      // state stores: lane 0 has x0 (row0 xA), lane 16 has x1 (xA) + x2 (xB)
      if (rl == 0) {
        yfb[t * 4] = xA;  // yf[t][0]=x0 (lane0) / yf[t][1]=x1 (lane16)
        ysb[t * 2] = xA;  // ys[t][0]=x0        / ys[t][1]=x1
        xsb[t * 3] = xA;  // xs[t][0]=x0        / xs[t][1]=x1
      }
      if (sub == 16) {
        yfb[t * 4 + 1] = xB;  // yf[t][2] = x2
        xsb[t * 3 + 1] = xB;  // xs[t][2] = x2
      }
      const float cA = __builtin_fmaf(us[e], uCoef, uBias);
      float k1A, k1B, k2A, k2B, k3A, k3B, k4A, k4B;
      fxu(xA, xB, cA, k1A, k1B);
      fxu(__builtin_fmaf(0.5f, k1A, xA), __builtin_fmaf(0.5f, k1B, xB), cA,
          k2A, k2B);
      fxu(__builtin_fmaf(0.5f, k2A, xA), __builtin_fmaf(0.5f, k2B, xB), cA,
          k3A, k3B);
      fxu(xA + k3A, xB + k3B, cA, k4A, k4B);
      float tA = k2A + k3A;
      tA = __builtin_fmaf(2.0f, tA, k1A) + k4A;
      xA = __builtin_fmaf(1.0f / 6.0f, tA, xA);
      float tB = k2B + k3B;
      tB = __builtin_fmaf(2.0f, tB, k1B) + k4B;
      xB = __builtin_fmaf(1.0f / 6.0f, tB, xB);
    }
    ucur = unext;
  }
}

// ---------------------------------------------------------------------------
// Phase 2: CcNN = eC(z_t) for all (b,t), fully parallel. One block per batch
// row; each thread does 4 consecutive t. Weights in LDS pre-scaled by
// TANH_SCALE; output weight folded into the rcp-fma:
//   Cc = b2 + sum_j W2_j*tanh(h_j) = (b2 + sum W2) + sum_j (-2*W2_j)*r_j
// -> inner body per (j,e) is exp2, add, rcp, fma (was 7 ops).
// ---------------------------------------------------------------------------
__global__ __launch_bounds__(256) void phase2_kernel(
    const float* __restrict__ u, const float* __restrict__ xz0,
    const float* __restrict__ eCW1, const float* __restrict__ eCb1,
    const float* __restrict__ eCW2, const float* __restrict__ eCb2,
    float* __restrict__ out) {
  __shared__ float lw[32][16];
  __shared__ float lw2[32];
  const int tid = threadIdx.x;
  if (tid < 32) {
#pragma unroll
    for (int i = 0; i < 15; ++i) lw[tid][i] = eCW1[i * 32 + tid] * TANH_SCALE;
    lw[tid][15] = eCb1[tid] * TANH_SCALE;
    lw2[tid] = -2.0f * eCW2[tid];
  }
  __syncthreads();

  const int b = blockIdx.x;
  const int t0 = tid << 2;
  const float2* ysrow =
      (const float2*)(out + (size_t)NB * NT * 4) + (size_t)b * NT;
  const float* urow = u + (size_t)b * NT;
  const float* xzr = xz0 + b * 18;

  // window: times t' = t0-5 .. t0+2; t' < 0 comes from z0 (entry t'+5)
  float yw[16], uw[8];
#pragma unroll
  for (int idx = 0; idx < 8; ++idx) {
    const int tp = t0 - 5 + idx;
    float a, c, uu;
    if (tp >= 0) {
      const float2 h = ysrow[tp];
      a = h.x;
      c = h.y;
      uu = urow[tp];
    } else {
      a = xzr[3 + 2 * (tp + 5)];
      c = xzr[4 + 2 * (tp + 5)];
      uu = xzr[13 + (tp + 5)];
    }
    yw[2 * idx] = a;
    yw[2 * idx + 1] = c;
    uw[idx] = uu;
  }

  float acc[4] = {0.f, 0.f, 0.f, 0.f};
  for (int j = 0; j < 32; ++j) {
    const float4 wa = ((const float4*)lw[j])[0];
    const float4 wb = ((const float4*)lw[j])[1];
    const float4 wc = ((const float4*)lw[j])[2];
    const float4 wd = ((const float4*)lw[j])[3];  // .w = scaled bias
    const float w2n = lw2[j];
#pragma unroll
    for (int e = 0; e < 4; ++e) {
      float h = wd.w;
      h = __builtin_fmaf(yw[2 * e + 0], wa.x, h);
      h = __builtin_fmaf(yw[2 * e + 1], wa.y, h);
      h = __builtin_fmaf(yw[2 * e + 2], wa.z, h);
      h = __builtin_fmaf(yw[2 * e + 3], wa.w, h);
      h = __builtin_fmaf(yw[2 * e + 4], wb.x, h);
      h = __builtin_fmaf(yw[2 * e + 5], wb.y, h);
      h = __builtin_fmaf(yw[2 * e + 6], wb.z, h);
      h = __builtin_fmaf(yw[2 * e + 7], wb.w, h);
      h = __builtin_fmaf(yw[2 * e + 8], wc.x, h);
      h = __builtin_fmaf(yw[2 * e + 9], wc.y, h);
      h = __builtin_fmaf(uw[e + 0], wc.z, h);
      h = __builtin_fmaf(uw[e + 1], wc.w, h);
      h = __builtin_fmaf(uw[e + 2], wd.x, h);
      h = __builtin_fmaf(uw[e + 3], wd.y, h);
      h = __builtin_fmaf(uw[e + 4], wd.z, h);
      const float r = RCPF(EXP2F(h) + 1.0f);
      acc[e] = __builtin_fmaf(w2n, r, acc[e]);
    }
  }
  // C = b2 + sum(W2) (uniform addresses -> scalar loads, one-time)
  float sw = 0.0f;
#pragma unroll
  for (int j = 0; j < 32; ++j) sw += eCW2[j];
  const float C = eCb2[0] + sw;
  float* yfrow = out + (size_t)b * NT * 4;
#pragma unroll
  for (int e = 0; e < 4; ++e) {
    yfrow[(t0 + e) * 4 + 3] = acc[e] + C;
  }
}

extern "C" void kernel_launch(void* const* d_in, const int* in_sizes, int n_in,
                              void* d_out, int out_size, void* d_ws,
                              size_t ws_size, hipStream_t stream) {
  const float* u = (const float*)d_in[0];
  const float* xz0 = (const float*)d_in[1];
  const float* r1W1 = (const float*)d_in[2];
  const float* r1b1 = (const float*)d_in[3];
  const float* r1W2 = (const float*)d_in[4];
  const float* r1b2 = (const float*)d_in[5];
  const float* r2W1 = (const float*)d_in[6];
  const float* r2b1 = (const float*)d_in[7];
  const float* r2W2 = (const float*)d_in[8];
  const float* r2b2 = (const float*)d_in[9];
  const float* eCW1 = (const float*)d_in[10];
  const float* eCb1 = (const float*)d_in[11];
  const float* eCW2 = (const float*)d_in[12];
  const float* eCb2 = (const float*)d_in[13];
  float* out = (float*)d_out;

  hipLaunchKernelGGL(phase1_kernel, dim3(NB / 8), dim3(256), 0, stream, u, xz0,
                     r1W1, r1b1, r1W2, r1b2, r2W1, r2b1, r2W2, r2b2, eCW1,
                     eCb1, eCW2, eCb2, out);
  hipLaunchKernelGGL(phase2_kernel, dim3(NB), dim3(256), 0, stream, u, xz0,
                     eCW1, eCb1, eCW2, eCb2, out);
}

// Round 2
// 584.762 us; speedup vs baseline: 1.1677x; 1.1677x over previous
//
#include <hip/hip_runtime.h>
#include <stdint.h>
#include <math.h>

#define NB 4096
#define NT 1024

// Output layout (float32, concatenated in return order):
//   yseq_full: [NB][NT][4]  at offset 0
//   yseq:      [NB][NT][2]  at offset NB*NT*4
//   xseq:      [NB][NT][3]  at offset NB*NT*6

#if __has_builtin(__builtin_amdgcn_exp2f)
#define EXP2F __builtin_amdgcn_exp2f
#else
#define EXP2F exp2f
#endif
#if __has_builtin(__builtin_amdgcn_rcpf)
#define RCPF __builtin_amdgcn_rcpf
#else
#define RCPF(x) (1.0f / (x))
#endif

// 2*log2(e): tanh(y) = 1 - 2/(1+exp2(y*TANH_SCALE)); scale folded into W1/b1.
#define TANH_SCALE 2.885390081777927f

// DPP move, masked-out lanes read 0 (bound_ctrl=1). Full-rate VALU cross-lane.
template <int CTRL>
__device__ __forceinline__ float dppmov(float x) {
  return __int_as_float(
      __builtin_amdgcn_update_dpp(0, __float_as_int(x), CTRL, 0xF, 0xF, true));
}

// allreduce over each 4-lane quad: quad_perm never crosses quad boundaries.
__device__ __forceinline__ float quadred(float a) {
  a += dppmov<0xB1>(a);  // quad_perm:[1,0,3,2] swap neighbors
  a += dppmov<0x4E>(a);  // quad_perm:[2,3,0,1] swap pairs
  return a;
}

// ---------------------------------------------------------------------------
// Phase 1: sequential x-recurrence.
// LAYOUT: 8 lanes per chain (8 chains per wave), 4 hidden units per lane.
//   quad 0 (lanes 0-3 of chain): the 16 r1 hidden units (4 per lane)
//   quad 1 (lanes 4-7 of chain): the 16 r2 hidden units (4 per lane)
// Cross-lane per stage: 2 quad_perm DPP-adds + 1 row_half_mirror DPP = 3-deep
// (was 5-deep: 4x ror + bcast). All lanes replicate k0,k1,k2 and the state:
// no bcast, no divergent stores. Rationale: wall/step was invariant at ~1190
// cyc across two different wave/issue structures => latency-walled on the
// serial chain; this cuts the chain, not just the issue count.
// ---------------------------------------------------------------------------
__global__ __launch_bounds__(64) void phase1_kernel(
    const float* __restrict__ u, const float* __restrict__ xz0,
    const float* __restrict__ r1W1, const float* __restrict__ r1b1,
    const float* __restrict__ r1W2, const float* __restrict__ r1b2,
    const float* __restrict__ r2W1, const float* __restrict__ r2b1,
    const float* __restrict__ r2W2, const float* __restrict__ r2b2,
    const float* __restrict__ eCW1, const float* __restrict__ eCb1,
    const float* __restrict__ eCW2, const float* __restrict__ eCb2,
    float* __restrict__ out) {
  const int tid = threadIdx.x;  // block = 64 threads = 1 wave
  const int cl = tid & 7;       // lane within chain
  const int q = tid & 3;        // lane within quad
  const bool isQ1 = (tid & 4) != 0;  // quad1 = r2 lanes
  const int chain = (blockIdx.x << 3) + (tid >> 3);

  // per-lane weights: 4 hidden units per lane, tanh scale folded in.
  float wA[4], wB[4], wC[4], wPn2[4];
  float wPsum = 0.0f;
#pragma unroll
  for (int m = 0; m < 4; ++m) {
    const int un = q + 4 * m;
    float wp;
    if (!isQ1) {
      wA[m] = r1W1[un] * TANH_SCALE;
      wB[m] = 0.0f;  // r1 has a single input
      wC[m] = r1b1[un] * TANH_SCALE;
      wp = r1W2[un];
    } else {
      wA[m] = r2W1[un] * TANH_SCALE;       // weight on s1
      wB[m] = r2W1[16 + un] * TANH_SCALE;  // weight on s2
      wC[m] = r2b1[un] * TANH_SCALE;
      wp = r2W2[un];
    }
    wPn2[m] = -2.0f * wp;
    wPsum += wp;  // Sum wP*tanh = wPsum + Sum wPn2_m * r_m
  }
  const float c1 = r1b2[0];
  const float c2 = r2b2[0];
  // k0 = (u/6 + 1/6 - c1) - 0.1 s0 - S1
  // k1 = (-0.2 + 1.5 c1 - 3 c2) - 0.1 s1 + 1.5 S1 - 3 S2
  // k2 = (c2 - 0.2)             - 0.1 s2 + S2
  const float C0b = 1.0f / 6.0f - c1;
  const float C1 = -0.2f + 1.5f * c1 - 3.0f * c2;
  const float C2 = c2 - 0.2f;
  // per-lane coefficients on (Sown, Soth): quad0 own=S1, quad1 own=S2
  const float aO0 = isQ1 ? 0.0f : -1.0f;
  const float aT0 = isQ1 ? -1.0f : 0.0f;
  const float aO1 = isQ1 ? -3.0f : 1.5f;
  const float aT1 = isQ1 ? 1.5f : -3.0f;
  const float aO2 = isQ1 ? 1.0f : 0.0f;
  const float aT2 = isQ1 ? 0.0f : 1.0f;

  const float* xzr = xz0 + chain * 18;
  float x0 = xzr[0];
  float x1 = xzr[1];
  float x2;

  // Cc0 = eC(z0): 32 hidden units = 4 per lane (units 4*cl..4*cl+3).
  {
    float eh[4], ewn2[4];
    float ewsum = 0.0f;
#pragma unroll
    for (int m = 0; m < 4; ++m) {
      const int un = 4 * cl + m;
      eh[m] = eCb1[un];
      ewn2[m] = -2.0f * eCW2[un];
      ewsum += eCW2[un];
    }
#pragma unroll
    for (int i = 0; i < 15; ++i) {
      const float z = xzr[3 + i];
#pragma unroll
      for (int m = 0; m < 4; ++m)
        eh[m] = __builtin_fmaf(z, eCW1[i * 32 + 4 * cl + m], eh[m]);
    }
    float pl = ewsum;
#pragma unroll
    for (int m = 0; m < 4; ++m) {
      const float e = EXP2F(eh[m] * TANH_SCALE);
      const float r = RCPF(e + 1.0f);
      pl = __builtin_fmaf(ewn2[m], r, pl);
    }
    pl = quadred(pl);             // per-quad 16-unit sums
    pl = pl + dppmov<0x141>(pl);  // add the other quad's sum
    x2 = pl + eCb2[0];
  }

  // branchless store plan: lane cl owns one output scalar per step.
  //   cl 0..2 -> yseq_full[chain][t][cl]      (stride 4 floats)
  //   cl 3..4 -> yseq[chain][t][cl-3]         (stride 2)
  //   cl 5..7 -> xseq[chain][t][cl-5]         (stride 3)
  size_t idx0;
  int stride;
  if (cl < 3) {
    idx0 = (size_t)chain * NT * 4 + cl;
    stride = 4;
  } else if (cl < 5) {
    idx0 = (size_t)NB * NT * 4 + (size_t)chain * NT * 2 + (cl - 3);
    stride = 2;
  } else {
    idx0 = (size_t)NB * NT * 6 + (size_t)chain * NT * 3 + (cl - 5);
    stride = 3;
  }
  float* sp = out + idx0;
  const bool selx0 = (cl == 0) || (cl == 3) || (cl == 5);
  const bool selx1 = (cl == 1) || (cl == 4) || (cl == 6);

  // one RK stage. u0/u1/u2 issue while tanh/reduce is in flight; post-reduce
  // chain is 2 fma deep.
  auto fxu = [&](float s0s, float s1s, float s2s, float C0t, float& k0,
                 float& k1, float& k2) {
    const float sU = isQ1 ? s1s : s0s;
    const float sV = isQ1 ? s2s : s0s;  // quad0: wB=0 -> inner fma = wC exact
    float r[4];
#pragma unroll
    for (int m = 0; m < 4; ++m) {
      float h = __builtin_fmaf(sV, wB[m], wC[m]);
      h = __builtin_fmaf(sU, wA[m], h);
      const float e = EXP2F(h);
      r[m] = RCPF(e + 1.0f);
    }
    float pl = wPsum;
#pragma unroll
    for (int m = 0; m < 4; ++m) pl = __builtin_fmaf(wPn2[m], r[m], pl);
    const float Sown = quadred(pl);
    const float Soth = dppmov<0x141>(Sown);  // other quad's sum
    const float u0 = __builtin_fmaf(-0.1f, s0s, C0t);
    const float u1 = __builtin_fmaf(-0.1f, s1s, C1);
    const float u2 = __builtin_fmaf(-0.1f, s2s, C2);
    k0 = __builtin_fmaf(aO0, Sown, u0);
    k1 = __builtin_fmaf(aO1, Sown, u1);
    k2 = __builtin_fmaf(aO2, Sown, u2);
    k0 = __builtin_fmaf(aT0, Soth, k0);
    k1 = __builtin_fmaf(aT1, Soth, k1);
    k2 = __builtin_fmaf(aT2, Soth, k2);
  };

  const float* urow = u + (size_t)chain * NT;
  float4 ucur = *(const float4*)urow;
  for (int t4 = 0; t4 < NT; t4 += 4) {
    const int tn = (t4 + 4 < NT) ? (t4 + 4) : (NT - 4);
    const float4 unext = *(const float4*)(urow + tn);  // prefetch next group
    const float us[4] = {ucur.x, ucur.y, ucur.z, ucur.w};
#pragma unroll
    for (int e = 0; e < 4; ++e) {
      // store state at t (branchless, full exec: one scalar per lane)
      const float v = selx0 ? x0 : (selx1 ? x1 : x2);
      *sp = v;
      sp += stride;
      const float C0t = __builtin_fmaf(us[e], 1.0f / 6.0f, C0b);
      float k10, k11, k12, k20, k21, k22, k30, k31, k32, k40, k41, k42;
      fxu(x0, x1, x2, C0t, k10, k11, k12);
      fxu(__builtin_fmaf(0.5f, k10, x0), __builtin_fmaf(0.5f, k11, x1),
          __builtin_fmaf(0.5f, k12, x2), C0t, k20, k21, k22);
      fxu(__builtin_fmaf(0.5f, k20, x0), __builtin_fmaf(0.5f, k21, x1),
          __builtin_fmaf(0.5f, k22, x2), C0t, k30, k31, k32);
      fxu(x0 + k30, x1 + k31, x2 + k32, C0t, k40, k41, k42);
      float tA = k20 + k30;
      tA = __builtin_fmaf(2.0f, tA, k10) + k40;
      x0 = __builtin_fmaf(1.0f / 6.0f, tA, x0);
      float tB = k21 + k31;
      tB = __builtin_fmaf(2.0f, tB, k11) + k41;
      x1 = __builtin_fmaf(1.0f / 6.0f, tB, x1);
      float tC = k22 + k32;
      tC = __builtin_fmaf(2.0f, tC, k12) + k42;
      x2 = __builtin_fmaf(1.0f / 6.0f, tC, x2);
    }
    ucur = unext;
  }
}

// ---------------------------------------------------------------------------
// Phase 2: CcNN = eC(z_t) for all (b,t), fully parallel. Unchanged from the
// verified round-1 version (weights pre-scaled by TANH_SCALE in LDS, output
// weight folded into the rcp-fma).
// ---------------------------------------------------------------------------
__global__ __launch_bounds__(256) void phase2_kernel(
    const float* __restrict__ u, const float* __restrict__ xz0,
    const float* __restrict__ eCW1, const float* __restrict__ eCb1,
    const float* __restrict__ eCW2, const float* __restrict__ eCb2,
    float* __restrict__ out) {
  __shared__ float lw[32][16];
  __shared__ float lw2[32];
  const int tid = threadIdx.x;
  if (tid < 32) {
#pragma unroll
    for (int i = 0; i < 15; ++i) lw[tid][i] = eCW1[i * 32 + tid] * TANH_SCALE;
    lw[tid][15] = eCb1[tid] * TANH_SCALE;
    lw2[tid] = -2.0f * eCW2[tid];
  }
  __syncthreads();

  const int b = blockIdx.x;
  const int t0 = tid << 2;
  const float2* ysrow =
      (const float2*)(out + (size_t)NB * NT * 4) + (size_t)b * NT;
  const float* urow = u + (size_t)b * NT;
  const float* xzr = xz0 + b * 18;

  // window: times t' = t0-5 .. t0+2; t' < 0 comes from z0 (entry t'+5)
  float yw[16], uw[8];
#pragma unroll
  for (int idx = 0; idx < 8; ++idx) {
    const int tp = t0 - 5 + idx;
    float a, c, uu;
    if (tp >= 0) {
      const float2 h = ysrow[tp];
      a = h.x;
      c = h.y;
      uu = urow[tp];
    } else {
      a = xzr[3 + 2 * (tp + 5)];
      c = xzr[4 + 2 * (tp + 5)];
      uu = xzr[13 + (tp + 5)];
    }
    yw[2 * idx] = a;
    yw[2 * idx + 1] = c;
    uw[idx] = uu;
  }

  float acc[4] = {0.f, 0.f, 0.f, 0.f};
  for (int j = 0; j < 32; ++j) {
    const float4 wa = ((const float4*)lw[j])[0];
    const float4 wb = ((const float4*)lw[j])[1];
    const float4 wc = ((const float4*)lw[j])[2];
    const float4 wd = ((const float4*)lw[j])[3];  // .w = scaled bias
    const float w2n = lw2[j];
#pragma unroll
    for (int e = 0; e < 4; ++e) {
      float h = wd.w;
      h = __builtin_fmaf(yw[2 * e + 0], wa.x, h);
      h = __builtin_fmaf(yw[2 * e + 1], wa.y, h);
      h = __builtin_fmaf(yw[2 * e + 2], wa.z, h);
      h = __builtin_fmaf(yw[2 * e + 3], wa.w, h);
      h = __builtin_fmaf(yw[2 * e + 4], wb.x, h);
      h = __builtin_fmaf(yw[2 * e + 5], wb.y, h);
      h = __builtin_fmaf(yw[2 * e + 6], wb.z, h);
      h = __builtin_fmaf(yw[2 * e + 7], wb.w, h);
      h = __builtin_fmaf(yw[2 * e + 8], wc.x, h);
      h = __builtin_fmaf(yw[2 * e + 9], wc.y, h);
      h = __builtin_fmaf(uw[e + 0], wc.z, h);
      h = __builtin_fmaf(uw[e + 1], wc.w, h);
      h = __builtin_fmaf(uw[e + 2], wd.x, h);
      h = __builtin_fmaf(uw[e + 3], wd.y, h);
      h = __builtin_fmaf(uw[e + 4], wd.z, h);
      const float r = RCPF(EXP2F(h) + 1.0f);
      acc[e] = __builtin_fmaf(w2n, r, acc[e]);
    }
  }
  // C = b2 + sum(W2) (uniform addresses -> scalar loads, one-time)
  float sw = 0.0f;
#pragma unroll
  for (int j = 0; j < 32; ++j) sw += eCW2[j];
  const float C = eCb2[0] + sw;
  float* yfrow = out + (size_t)b * NT * 4;
#pragma unroll
  for (int e = 0; e < 4; ++e) {
    yfrow[(t0 + e) * 4 + 3] = acc[e] + C;
  }
}

extern "C" void kernel_launch(void* const* d_in, const int* in_sizes, int n_in,
                              void* d_out, int out_size, void* d_ws,
                              size_t ws_size, hipStream_t stream) {
  const float* u = (const float*)d_in[0];
  const float* xz0 = (const float*)d_in[1];
  const float* r1W1 = (const float*)d_in[2];
  const float* r1b1 = (const float*)d_in[3];
  const float* r1W2 = (const float*)d_in[4];
  const float* r1b2 = (const float*)d_in[5];
  const float* r2W1 = (const float*)d_in[6];
  const float* r2b1 = (const float*)d_in[7];
  const float* r2W2 = (const float*)d_in[8];
  const float* r2b2 = (const float*)d_in[9];
  const float* eCW1 = (const float*)d_in[10];
  const float* eCb1 = (const float*)d_in[11];
  const float* eCW2 = (const float*)d_in[12];
  const float* eCb2 = (const float*)d_in[13];
  float* out = (float*)d_out;

  hipLaunchKernelGGL(phase1_kernel, dim3(NB / 8), dim3(64), 0, stream, u, xz0,
                     r1W1, r1b1, r1W2, r1b2, r2W1, r2b1, r2W2, r2b2, eCW1,
                     eCb1, eCW2, eCb2, out);
  hipLaunchKernelGGL(phase2_kernel, dim3(NB), dim3(256), 0, stream, u, xz0,
                     eCW1, eCb1, eCW2, eCb2, out);
}